// Round 5
// baseline (258.890 us; speedup 1.0000x reference)
//
#include <hip/hip_runtime.h>

typedef __attribute__((ext_vector_type(8))) short short8;
typedef __attribute__((ext_vector_type(4))) float f32x4;
typedef __attribute__((ext_vector_type(16))) float f32x16;

#define B_ 2
#define N_ 2048
#define C_ 1024
#define H_ 16
#define SCALE_ 0.03125f

__device__ inline unsigned short f2bf(float f) {
    unsigned int u = __float_as_uint(f);
    return (unsigned short)((u + 0x7fffu + ((u >> 16) & 1u)) >> 16);
}

__device__ inline f32x4 mfma16(short8 a, short8 b, f32x4 c) {
    return __builtin_amdgcn_mfma_f32_16x16x32_bf16(a, b, c, 0, 0, 0);
}
__device__ inline f32x16 mfma32(short8 a, short8 b, f32x16 c) {
    return __builtin_amdgcn_mfma_f32_32x32x16_bf16(a, b, c, 0, 0, 0);
}

#define GLOAD_LDS16(g, l) __builtin_amdgcn_global_load_lds( \
    (const __attribute__((address_space(1))) void*)(g),     \
    (__attribute__((address_space(3))) void*)(l), 16, 0, 0)

// ---------------- fused fp32 -> bf16 convert ----------------
__global__ void cvt_all(const float* __restrict__ x, const float* __restrict__ wq,
                        const float* __restrict__ wp, unsigned short* __restrict__ xb,
                        unsigned short* __restrict__ wqb, unsigned short* __restrict__ wpb) {
    int i = blockIdx.x * blockDim.x + threadIdx.x;
    const int n1 = 4096 * 1024 / 4, n2 = 3072 * 1024 / 4;
    const float* src; unsigned short* dst; int j;
    if (i < n1)            { src = x;  dst = xb;  j = i; }
    else if (i < n1 + n2)  { src = wq; dst = wqb; j = i - n1; }
    else                   { src = wp; dst = wpb; j = i - n1 - n2; }
    float4 v = *(const float4*)(src + (size_t)j * 4);
    ushort4 o;
    o.x = f2bf(v.x); o.y = f2bf(v.y); o.z = f2bf(v.z); o.w = f2bf(v.w);
    *(ushort4*)(dst + (size_t)j * 4) = o;
}

// ---------------- bf16 B^T GEMM, BMx128 tile, BK=64, XCD-chunked 1D grid ----------------
template<int BF16_OUT, int BM>
__global__ __launch_bounds__(256, 3)
void gemm_bt(const unsigned short* __restrict__ A, const unsigned short* __restrict__ Bm,
             unsigned short* __restrict__ Cb, float* __restrict__ Cf,
             const float* __restrict__ bias, int M, int N, int K, int nxt) {
    constexpr int AI = BM / 32;
    __shared__ unsigned short lA[BM * 64];
    __shared__ unsigned short lB[128 * 64];
    const int tid = threadIdx.x;
    const int lane = tid & 63, wave = tid >> 6;
    const int lm = lane & 15, g = lane >> 4;
    const int flat = blockIdx.x, per = gridDim.x >> 3;
    const int f2 = (flat & 7) * per + (flat >> 3);
    const int by = f2 / nxt, bx = f2 - by * nxt;
    const int m0 = by * BM, n0 = bx * 128;
    const int wr = wave >> 1, wc = wave & 1;

    f32x4 acc[AI][4];
    f32x4 zero = {0.f, 0.f, 0.f, 0.f};
#pragma unroll
    for (int i = 0; i < AI; ++i)
#pragma unroll
        for (int j = 0; j < 4; ++j) acc[i][j] = zero;

    const int sRow = lane >> 3;
    const int sCol = (lane & 7) * 8;

    for (int k0 = 0; k0 < K; k0 += 64) {
#pragma unroll
        for (int t = 0; t < AI; ++t) {
            int inst = wave * AI + t;
            int r = inst * 8 + sRow;
            GLOAD_LDS16(A + (size_t)(m0 + r) * K + k0 + sCol, lA + inst * 512);
        }
#pragma unroll
        for (int t = 0; t < 4; ++t) {
            int inst = wave * 4 + t;
            int r = inst * 8 + sRow;
            GLOAD_LDS16(Bm + (size_t)(n0 + r) * K + k0 + sCol, lB + inst * 512);
        }
        __syncthreads();
#pragma unroll
        for (int kk = 0; kk < 2; ++kk) {
            short8 af[AI], bfv[4];
#pragma unroll
            for (int i = 0; i < AI; ++i)
                af[i] = *(const short8*)&lA[(wr * (BM / 2) + i * 16 + lm) * 64 + kk * 32 + g * 8];
#pragma unroll
            for (int j = 0; j < 4; ++j)
                bfv[j] = *(const short8*)&lB[(wc * 64 + j * 16 + lm) * 64 + kk * 32 + g * 8];
#pragma unroll
            for (int i = 0; i < AI; ++i)
#pragma unroll
                for (int j = 0; j < 4; ++j)
                    acc[i][j] = mfma16(af[i], bfv[j], acc[i][j]);
        }
        __syncthreads();
    }
#pragma unroll
    for (int i = 0; i < AI; ++i) {
#pragma unroll
        for (int j = 0; j < 4; ++j) {
#pragma unroll
            for (int r = 0; r < 4; ++r) {
                int m = m0 + wr * (BM / 2) + i * 16 + g * 4 + r;
                int n = n0 + wc * 64 + j * 16 + lm;
                float v = acc[i][j][r];
                if (BF16_OUT)
                    Cb[(size_t)m * N + n] = f2bf(v);
                else
                    Cf[(size_t)m * N + n] = v + bias[n];
            }
        }
    }
}

// ---------------- attention staging: XOR-pre-swizzled K -> linear LDS ----------------
__device__ inline void stage_k256(const unsigned short* kbase, unsigned short* buf, int tid) {
    const int wave = tid >> 6, lane = tid & 63;
#pragma unroll
    for (int i = 0; i < 2; ++i) {
        int c = i * 256 + wave * 64 + lane;
        int row = c >> 3, j = c & 7;
        GLOAD_LDS16(kbase + (size_t)row * 3072 + ((j ^ (row & 7)) << 3),
                    buf + (i * 256 + wave * 64) * 8);
    }
}
__device__ inline void stage_k128(const unsigned short* kbase, unsigned short* buf, int tid) {
    const int wave = tid >> 6, lane = tid & 63;
#pragma unroll
    for (int i = 0; i < 4; ++i) {
        int c = i * 128 + wave * 64 + lane;
        int row = c >> 3, j = c & 7;
        GLOAD_LDS16(kbase + (size_t)row * 3072 + ((j ^ (row & 7)) << 3),
                    buf + (i * 128 + wave * 64) * 8);
    }
}

// ---------------- attn kernel 1: softmax denominators (32x32 MFMA) ----------------
__global__ __launch_bounds__(128, 2)
void attn_sums(const unsigned short* __restrict__ qkv, float* __restrict__ rinv_out) {
    __shared__ unsigned short kt[2 * 4096];
    const int tid = threadIdx.x, lane = tid & 63, wave = tid >> 6;
    const int l31 = lane & 31, h5 = lane >> 5, l7 = lane & 7;
    const int flat = blockIdx.x;
    const int work = ((flat & 7) << 7) | (flat >> 3);
    const int q0 = (work & 31) * 64, h = (work >> 5) & 15, b = work >> 9;
    const unsigned short* qkvB = qkv + (size_t)b * N_ * 3072;
    const unsigned short* kh = qkvB + 1024 + h * 64;

    const unsigned short* qrow = qkvB + (size_t)(q0 + wave * 32 + l31) * 3072 + h * 64;
    short8 aq[4];
#pragma unroll
    for (int ks = 0; ks < 4; ++ks) aq[ks] = *(const short8*)(qrow + ks * 16 + h5 * 8);

    float part[16];
#pragma unroll
    for (int i = 0; i < 16; ++i) part[i] = 0.f;

    stage_k128(kh, kt, tid);
    __syncthreads();

    for (int kti = 0; kti < 32; ++kti) {
        const int cur = kti & 1;
        if (kti < 31) stage_k128(kh + (size_t)(kti + 1) * 196608, kt + (cur ^ 1) * 4096, tid);
        const unsigned short* ktc = kt + cur * 4096;
        f32x16 s0 = {}, s1 = {};
        __builtin_amdgcn_s_setprio(1);
#pragma unroll
        for (int ks = 0; ks < 4; ++ks) {
            int ch = ((ks * 2 + h5) ^ l7) * 8;
            short8 b0 = *(const short8*)&ktc[l31 * 64 + ch];
            short8 b1 = *(const short8*)&ktc[(32 + l31) * 64 + ch];
            s0 = mfma32(aq[ks], b0, s0);
            s1 = mfma32(aq[ks], b1, s1);
        }
        __builtin_amdgcn_s_setprio(0);
#pragma unroll
        for (int r = 0; r < 16; ++r)
            part[r] += __expf(s0[r] * SCALE_) + __expf(s1[r] * SCALE_);
        __syncthreads();
    }
#pragma unroll
    for (int r = 0; r < 16; ++r) {
#pragma unroll
        for (int off = 1; off < 32; off <<= 1) part[r] += __shfl_xor(part[r], off);
    }
    if (l31 == 0) {
        float* base = rinv_out + (size_t)(b * H_ + h) * N_ + q0 + wave * 32 + 4 * h5;
#pragma unroll
        for (int r = 0; r < 16; ++r) base[(r & 3) + 8 * (r >> 2)] = 1.0f / part[r];
    }
}

// ---------------- attn kernel 2: attn write + PV (32x32 MFMA) ----------------
// Grid 512 = 2 blocks/CU. ONE raw barrier per tile: s_waitcnt vmcnt(32)
// lgkmcnt(0) + s_barrier. vmcnt issue order/tile = [2 K-stage][2 V-load]
// [32 attn stores]: vmcnt(32) retires staging/V but lets stores drain lazily
// across tiles (no per-tile store drain). pq and vt double-buffered so the
// single barrier separates all cross-wave hazards.
__global__ __launch_bounds__(256, 2)
void attn_write(const unsigned short* __restrict__ qkv, const float* __restrict__ rinv_in,
                float* __restrict__ attn_out, unsigned short* __restrict__ o_out) {
    __shared__ unsigned short smem[35840];       // 71,680 B -> 2 blocks/CU
    unsigned short* kt = smem;                   // [2][64][64] swizzled K (16 KB)
    unsigned short* vt = smem + 8192;            // [2][64 d][72] swizzled V^T (18 KB)
    unsigned short* pq = smem + 17408;           // [2][128][72] bf16 P (36 KB)

    const int tid = threadIdx.x, lane = tid & 63, wave = tid >> 6;
    const int l31 = lane & 31, h5 = lane >> 5, l7 = lane & 7;
    const int flat = blockIdx.x;
    const int work = ((flat & 7) << 6) | (flat >> 3);
    const int q0 = (work & 15) * 128, h = (work >> 4) & 15, b = work >> 8;
    const unsigned short* qkvB = qkv + (size_t)b * N_ * 3072;
    const unsigned short* kh = qkvB + 1024 + h * 64;
    const unsigned short* vh = qkvB + 2048 + h * 64;

    const unsigned short* qrow = qkvB + (size_t)(q0 + wave * 32 + l31) * 3072 + h * 64;
    short8 aq[4];
#pragma unroll
    for (int ks = 0; ks < 4; ++ks) aq[ks] = *(const short8*)(qrow + ks * 16 + h5 * 8);

    float rv[16];
    {
        const float* base = rinv_in + (size_t)(b * H_ + h) * N_ + q0 + wave * 32 + 4 * h5;
#pragma unroll
        for (int r = 0; r < 16; ++r) rv[r] = base[(r & 3) + 8 * (r >> 2)];
    }

    const int rV = (tid >> 3) * 2, cV = (tid & 7) * 8;
    short8 va, vb;
#define WRITEV(buf) do { _Pragma("unroll") for (int j = 0; j < 8; ++j) { \
        int d = cV + j; int w = (rV >> 1) ^ (((d >> 3) & 7) << 2);       \
        unsigned int pk = (unsigned int)(unsigned short)va[j] |          \
                          ((unsigned int)(unsigned short)vb[j] << 16);   \
        *(unsigned int*)&vt[(buf) * 4608 + d * 72 + 2 * w] = pk; } } while (0)

    // prologue: stage K0 -> kt[0], V0 -> vt[0]
    stage_k256(kh, kt, tid);
    {
        const unsigned short* sv = vh + (size_t)rV * 3072 + cV;
        va = *(const short8*)sv; vb = *(const short8*)(sv + 3072);
    }
    WRITEV(0);
    __syncthreads();

    f32x16 oa0 = {}, oa1 = {};
    float* attnB = attn_out + ((size_t)(b * H_ + h) * N_ + q0) * N_;

    for (int kti = 0; kti < 32; ++kti) {
        const int cur = kti & 1;
        // --- VMEM issue (oldest first): K-stage, V-loads, then stores below ---
        if (kti < 31) {
            stage_k256(kh + (size_t)(kti + 1) * 196608, kt + (cur ^ 1) * 4096, tid);
            const unsigned short* sv = vh + (size_t)(kti + 1) * 196608 + (size_t)rV * 3072 + cV;
            va = *(const short8*)sv; vb = *(const short8*)(sv + 3072);
        }
        // --- QK^T from kt[cur] (staged last iter, synced by last barrier) ---
        const unsigned short* ktc = kt + cur * 4096;
        f32x16 s0 = {}, s1 = {};
        __builtin_amdgcn_s_setprio(1);
#pragma unroll
        for (int ks = 0; ks < 4; ++ks) {
            int ch = ((ks * 2 + h5) ^ l7) * 8;
            short8 b0 = *(const short8*)&ktc[l31 * 64 + ch];
            short8 b1 = *(const short8*)&ktc[(32 + l31) * 64 + ch];
            s0 = mfma32(aq[ks], b0, s0);
            s1 = mfma32(aq[ks], b1, s1);
        }
        __builtin_amdgcn_s_setprio(0);

        // --- normalized attn stores (fp32) + bf16 P into pq[cur] ---
        float* aB = attnB + (size_t)(wave * 32 + 4 * h5) * N_ + kti * 64 + l31;
        unsigned short* pqw = pq + cur * 9216 + (wave * 32 + 4 * h5) * 72 + l31;
#pragma unroll
        for (int r = 0; r < 16; ++r) {
            int ro = (r & 3) + 8 * (r >> 2);
            float p0 = __expf(s0[r] * SCALE_) * rv[r];
            float p1 = __expf(s1[r] * SCALE_) * rv[r];
            aB[(size_t)ro * N_] = p0;
            aB[(size_t)ro * N_ + 32] = p1;
            pqw[ro * 72] = f2bf(p0);
            pqw[ro * 72 + 32] = f2bf(p1);
        }

        // --- single barrier: staging/V retired (vmcnt<=32), stores may linger ---
        asm volatile("s_waitcnt vmcnt(32) lgkmcnt(0)\n\ts_barrier" ::: "memory");
        __builtin_amdgcn_sched_barrier(0);

        // --- PV from pq[cur], vt[cur] ---
        __builtin_amdgcn_s_setprio(1);
#pragma unroll
        for (int ks = 0; ks < 4; ++ks) {
            short8 ap = *(const short8*)&pq[cur * 9216 + (wave * 32 + l31) * 72 + ks * 16 + h5 * 8];
            int wv0 = (ks * 8 + h5 * 4) ^ (((l31 >> 3) & 7) << 2);
            short8 bv0 = *(const short8*)&vt[cur * 4608 + l31 * 72 + 2 * wv0];
            int dch = 32 + l31;
            int wv1 = (ks * 8 + h5 * 4) ^ (((dch >> 3) & 7) << 2);
            short8 bv1 = *(const short8*)&vt[cur * 4608 + dch * 72 + 2 * wv1];
            oa0 = mfma32(ap, bv0, oa0);
            oa1 = mfma32(ap, bv1, oa1);
        }
        __builtin_amdgcn_s_setprio(0);

        // --- V^T for next tile into vt[cur^1] (post-PV; visible after next barrier) ---
        if (kti < 31) WRITEV(cur ^ 1);
    }

    // ---- write O (bf16, [B,N,C]) ----
#pragma unroll
    for (int r = 0; r < 16; ++r) {
        int qrw = q0 + wave * 32 + 4 * h5 + (r & 3) + 8 * (r >> 2);
        size_t ob = (size_t)(b * N_ + qrw) * C_ + h * 64 + l31;
        o_out[ob] = f2bf(oa0[r]);
        o_out[ob + 32] = f2bf(oa1[r]);
    }
#undef WRITEV
}

extern "C" void kernel_launch(void* const* d_in, const int* in_sizes, int n_in,
                              void* d_out, int out_size, void* d_ws, size_t ws_size,
                              hipStream_t stream) {
    (void)in_sizes; (void)n_in; (void)out_size; (void)ws_size;
    const float* x      = (const float*)d_in[0];
    const float* w_qkv  = (const float*)d_in[1];
    const float* w_proj = (const float*)d_in[2];
    const float* b_proj = (const float*)d_in[3];

    float* out  = (float*)d_out;                       // [2,2048,1024] fp32
    float* attn = out + (size_t)B_ * N_ * C_;          // [2,16,2048,2048] fp32

    unsigned short* x_b     = (unsigned short*)d_ws;            // 4096x1024 (dead after qkv GEMM)
    unsigned short* wqkv_b  = x_b + (size_t)4096 * 1024;        // 3072x1024
    unsigned short* wproj_b = wqkv_b + (size_t)3072 * 1024;     // 1024x1024
    unsigned short* qkv_b   = wproj_b + (size_t)1024 * 1024;    // 4096x3072
    unsigned short* o_b     = qkv_b + (size_t)4096 * 3072;      // 4096x1024
    float* rinv = (float*)x_b;                                  // reuse dead region

    cvt_all<<<8192, 256, 0, stream>>>(x, w_qkv, w_proj, x_b, wqkv_b, wproj_b);

    gemm_bt<1, 128><<<768, 256, 0, stream>>>(
        x_b, wqkv_b, qkv_b, nullptr, nullptr, 4096, 3072, 1024, 24);

    attn_sums<<<1024, 128, 0, stream>>>(qkv_b, rinv);
    attn_write<<<512, 256, 0, stream>>>(qkv_b, rinv, attn, o_b);

    gemm_bt<0, 64><<<512, 256, 0, stream>>>(
        o_b, wproj_b, nullptr, out, b_proj, 4096, 1024, 1024, 8);
}

// Round 6
// 234.239 us; speedup vs baseline: 1.1052x; 1.1052x over previous
//
#include <hip/hip_runtime.h>

typedef __attribute__((ext_vector_type(8))) short short8;
typedef __attribute__((ext_vector_type(4))) float f32x4;
typedef __attribute__((ext_vector_type(16))) float f32x16;

#define B_ 2
#define N_ 2048
#define C_ 1024
#define H_ 16
#define SCALE_ 0.03125f

__device__ inline unsigned short f2bf(float f) {
    unsigned int u = __float_as_uint(f);
    return (unsigned short)((u + 0x7fffu + ((u >> 16) & 1u)) >> 16);
}

__device__ inline f32x4 mfma16(short8 a, short8 b, f32x4 c) {
    return __builtin_amdgcn_mfma_f32_16x16x32_bf16(a, b, c, 0, 0, 0);
}
__device__ inline f32x16 mfma32(short8 a, short8 b, f32x16 c) {
    return __builtin_amdgcn_mfma_f32_32x32x16_bf16(a, b, c, 0, 0, 0);
}

#define GLOAD_LDS16(g, l) __builtin_amdgcn_global_load_lds( \
    (const __attribute__((address_space(1))) void*)(g),     \
    (__attribute__((address_space(3))) void*)(l), 16, 0, 0)

// ---------------- fused fp32 -> bf16 convert ----------------
__global__ void cvt_all(const float* __restrict__ x, const float* __restrict__ wq,
                        const float* __restrict__ wp, unsigned short* __restrict__ xb,
                        unsigned short* __restrict__ wqb, unsigned short* __restrict__ wpb) {
    int i = blockIdx.x * blockDim.x + threadIdx.x;
    const int n1 = 4096 * 1024 / 4, n2 = 3072 * 1024 / 4;
    const float* src; unsigned short* dst; int j;
    if (i < n1)            { src = x;  dst = xb;  j = i; }
    else if (i < n1 + n2)  { src = wq; dst = wqb; j = i - n1; }
    else                   { src = wp; dst = wpb; j = i - n1 - n2; }
    float4 v = *(const float4*)(src + (size_t)j * 4);
    ushort4 o;
    o.x = f2bf(v.x); o.y = f2bf(v.y); o.z = f2bf(v.z); o.w = f2bf(v.w);
    *(ushort4*)(dst + (size_t)j * 4) = o;
}

// ---------------- bf16 B^T GEMM, BMx128 tile, BK=64 ----------------
// Per-XCD rectangular tile regions (rpr by-rows x bxr bx-cols, bx-fastest) so the
// region's B-panel (bxr*256KB) fits the 4MB XCD L2 and is re-swept from L2, not HBM.
template<int BF16_OUT, int BM>
__global__ __launch_bounds__(256, 3)
void gemm_bt(const unsigned short* __restrict__ A, const unsigned short* __restrict__ Bm,
             unsigned short* __restrict__ Cb, float* __restrict__ Cf,
             const float* __restrict__ bias, int M, int N, int K,
             int xcd_cols, int bxr) {
    constexpr int AI = BM / 32;
    __shared__ unsigned short lA[BM * 64];
    __shared__ unsigned short lB[128 * 64];
    const int tid = threadIdx.x;
    const int lane = tid & 63, wave = tid >> 6;
    const int lm = lane & 15, g = lane >> 4;
    const int flat = blockIdx.x, per = gridDim.x >> 3;
    const int xcd = flat & 7, fl = flat >> 3;
    const int rpr = per / bxr;                    // by-rows per XCD region
    const int by = (xcd / xcd_cols) * rpr + fl / bxr;
    const int bx = (xcd % xcd_cols) * bxr + fl % bxr;
    const int m0 = by * BM, n0 = bx * 128;
    const int wr = wave >> 1, wc = wave & 1;

    f32x4 acc[AI][4];
    f32x4 zero = {0.f, 0.f, 0.f, 0.f};
#pragma unroll
    for (int i = 0; i < AI; ++i)
#pragma unroll
        for (int j = 0; j < 4; ++j) acc[i][j] = zero;

    const int sRow = lane >> 3;
    const int sCol = (lane & 7) * 8;

    for (int k0 = 0; k0 < K; k0 += 64) {
#pragma unroll
        for (int t = 0; t < AI; ++t) {
            int inst = wave * AI + t;
            int r = inst * 8 + sRow;
            GLOAD_LDS16(A + (size_t)(m0 + r) * K + k0 + sCol, lA + inst * 512);
        }
#pragma unroll
        for (int t = 0; t < 4; ++t) {
            int inst = wave * 4 + t;
            int r = inst * 8 + sRow;
            GLOAD_LDS16(Bm + (size_t)(n0 + r) * K + k0 + sCol, lB + inst * 512);
        }
        __syncthreads();
#pragma unroll
        for (int kk = 0; kk < 2; ++kk) {
            short8 af[AI], bfv[4];
#pragma unroll
            for (int i = 0; i < AI; ++i)
                af[i] = *(const short8*)&lA[(wr * (BM / 2) + i * 16 + lm) * 64 + kk * 32 + g * 8];
#pragma unroll
            for (int j = 0; j < 4; ++j)
                bfv[j] = *(const short8*)&lB[(wc * 64 + j * 16 + lm) * 64 + kk * 32 + g * 8];
#pragma unroll
            for (int i = 0; i < AI; ++i)
#pragma unroll
                for (int j = 0; j < 4; ++j)
                    acc[i][j] = mfma16(af[i], bfv[j], acc[i][j]);
        }
        __syncthreads();
    }
#pragma unroll
    for (int i = 0; i < AI; ++i) {
#pragma unroll
        for (int j = 0; j < 4; ++j) {
#pragma unroll
            for (int r = 0; r < 4; ++r) {
                int m = m0 + wr * (BM / 2) + i * 16 + g * 4 + r;
                int n = n0 + wc * 64 + j * 16 + lm;
                float v = acc[i][j][r];
                if (BF16_OUT)
                    Cb[(size_t)m * N + n] = f2bf(v);
                else
                    Cf[(size_t)m * N + n] = v + bias[n];
            }
        }
    }
}

// ---------------- attention staging: XOR-pre-swizzled K -> linear LDS ----------------
__device__ inline void stage_k256(const unsigned short* kbase, unsigned short* buf, int tid) {
    const int wave = tid >> 6, lane = tid & 63;
#pragma unroll
    for (int i = 0; i < 2; ++i) {
        int c = i * 256 + wave * 64 + lane;
        int row = c >> 3, j = c & 7;
        GLOAD_LDS16(kbase + (size_t)row * 3072 + ((j ^ (row & 7)) << 3),
                    buf + (i * 256 + wave * 64) * 8);
    }
}
__device__ inline void stage_k128(const unsigned short* kbase, unsigned short* buf, int tid) {
    const int wave = tid >> 6, lane = tid & 63;
#pragma unroll
    for (int i = 0; i < 4; ++i) {
        int c = i * 128 + wave * 64 + lane;
        int row = c >> 3, j = c & 7;
        GLOAD_LDS16(kbase + (size_t)row * 3072 + ((j ^ (row & 7)) << 3),
                    buf + (i * 128 + wave * 64) * 8);
    }
}

// ---------------- attn kernel 1: softmax denominators (32x32 MFMA) ----------------
__global__ __launch_bounds__(128, 2)
void attn_sums(const unsigned short* __restrict__ qkv, float* __restrict__ rinv_out) {
    __shared__ unsigned short kt[2 * 4096];
    const int tid = threadIdx.x, lane = tid & 63, wave = tid >> 6;
    const int l31 = lane & 31, h5 = lane >> 5, l7 = lane & 7;
    const int flat = blockIdx.x;
    const int work = ((flat & 7) << 7) | (flat >> 3);
    const int q0 = (work & 31) * 64, h = (work >> 5) & 15, b = work >> 9;
    const unsigned short* qkvB = qkv + (size_t)b * N_ * 3072;
    const unsigned short* kh = qkvB + 1024 + h * 64;

    const unsigned short* qrow = qkvB + (size_t)(q0 + wave * 32 + l31) * 3072 + h * 64;
    short8 aq[4];
#pragma unroll
    for (int ks = 0; ks < 4; ++ks) aq[ks] = *(const short8*)(qrow + ks * 16 + h5 * 8);

    float part[16];
#pragma unroll
    for (int i = 0; i < 16; ++i) part[i] = 0.f;

    stage_k128(kh, kt, tid);
    __syncthreads();

    for (int kti = 0; kti < 32; ++kti) {
        const int cur = kti & 1;
        if (kti < 31) stage_k128(kh + (size_t)(kti + 1) * 196608, kt + (cur ^ 1) * 4096, tid);
        const unsigned short* ktc = kt + cur * 4096;
        f32x16 s0 = {}, s1 = {};
        __builtin_amdgcn_s_setprio(1);
#pragma unroll
        for (int ks = 0; ks < 4; ++ks) {
            int ch = ((ks * 2 + h5) ^ l7) * 8;
            short8 b0 = *(const short8*)&ktc[l31 * 64 + ch];
            short8 b1 = *(const short8*)&ktc[(32 + l31) * 64 + ch];
            s0 = mfma32(aq[ks], b0, s0);
            s1 = mfma32(aq[ks], b1, s1);
        }
        __builtin_amdgcn_s_setprio(0);
#pragma unroll
        for (int r = 0; r < 16; ++r)
            part[r] += __expf(s0[r] * SCALE_) + __expf(s1[r] * SCALE_);
        __syncthreads();
    }
#pragma unroll
    for (int r = 0; r < 16; ++r) {
#pragma unroll
        for (int off = 1; off < 32; off <<= 1) part[r] += __shfl_xor(part[r], off);
    }
    if (l31 == 0) {
        float* base = rinv_out + (size_t)(b * H_ + h) * N_ + q0 + wave * 32 + 4 * h5;
#pragma unroll
        for (int r = 0; r < 16; ++r) base[(r & 3) + 8 * (r >> 2)] = 1.0f / part[r];
    }
}

// ---------------- attn kernel 2: attn write + PV (32x32 MFMA) ----------------
// Grid 512 = 2 blocks/CU. One barrier/tile with counted vmcnt (stores drain
// lazily). Attn stores are NONTEMPORAL: 537MB write-once must not evict the
// XCD-shared K/V working set (~2MB/XCD) from L2.
__global__ __launch_bounds__(256, 2)
void attn_write(const unsigned short* __restrict__ qkv, const float* __restrict__ rinv_in,
                float* __restrict__ attn_out, unsigned short* __restrict__ o_out) {
    __shared__ unsigned short smem[35840];       // 71,680 B -> 2 blocks/CU
    unsigned short* kt = smem;                   // [2][64][64] swizzled K (16 KB)
    unsigned short* vt = smem + 8192;            // [2][64 d][72] swizzled V^T (18 KB)
    unsigned short* pq = smem + 17408;           // [2][128][72] bf16 P (36 KB)

    const int tid = threadIdx.x, lane = tid & 63, wave = tid >> 6;
    const int l31 = lane & 31, h5 = lane >> 5, l7 = lane & 7;
    const int flat = blockIdx.x;
    const int work = ((flat & 7) << 6) | (flat >> 3);
    const int q0 = (work & 15) * 128, h = (work >> 4) & 15, b = work >> 8;
    const unsigned short* qkvB = qkv + (size_t)b * N_ * 3072;
    const unsigned short* kh = qkvB + 1024 + h * 64;
    const unsigned short* vh = qkvB + 2048 + h * 64;

    const unsigned short* qrow = qkvB + (size_t)(q0 + wave * 32 + l31) * 3072 + h * 64;
    short8 aq[4];
#pragma unroll
    for (int ks = 0; ks < 4; ++ks) aq[ks] = *(const short8*)(qrow + ks * 16 + h5 * 8);

    float rv[16];
    {
        const float* base = rinv_in + (size_t)(b * H_ + h) * N_ + q0 + wave * 32 + 4 * h5;
#pragma unroll
        for (int r = 0; r < 16; ++r) rv[r] = base[(r & 3) + 8 * (r >> 2)];
    }

    const int rV = (tid >> 3) * 2, cV = (tid & 7) * 8;
    short8 va, vb;
#define WRITEV(buf) do { _Pragma("unroll") for (int j = 0; j < 8; ++j) { \
        int d = cV + j; int w = (rV >> 1) ^ (((d >> 3) & 7) << 2);       \
        unsigned int pk = (unsigned int)(unsigned short)va[j] |          \
                          ((unsigned int)(unsigned short)vb[j] << 16);   \
        *(unsigned int*)&vt[(buf) * 4608 + d * 72 + 2 * w] = pk; } } while (0)

    // prologue: stage K0 -> kt[0], V0 -> vt[0]
    stage_k256(kh, kt, tid);
    {
        const unsigned short* sv = vh + (size_t)rV * 3072 + cV;
        va = *(const short8*)sv; vb = *(const short8*)(sv + 3072);
    }
    WRITEV(0);
    __syncthreads();

    f32x16 oa0 = {}, oa1 = {};
    float* attnB = attn_out + ((size_t)(b * H_ + h) * N_ + q0) * N_;

    for (int kti = 0; kti < 32; ++kti) {
        const int cur = kti & 1;
        // --- VMEM issue (oldest first): K-stage, V-loads, then stores below ---
        if (kti < 31) {
            stage_k256(kh + (size_t)(kti + 1) * 196608, kt + (cur ^ 1) * 4096, tid);
            const unsigned short* sv = vh + (size_t)(kti + 1) * 196608 + (size_t)rV * 3072 + cV;
            va = *(const short8*)sv; vb = *(const short8*)(sv + 3072);
        }
        // --- QK^T from kt[cur] ---
        const unsigned short* ktc = kt + cur * 4096;
        f32x16 s0 = {}, s1 = {};
        __builtin_amdgcn_s_setprio(1);
#pragma unroll
        for (int ks = 0; ks < 4; ++ks) {
            int ch = ((ks * 2 + h5) ^ l7) * 8;
            short8 b0 = *(const short8*)&ktc[l31 * 64 + ch];
            short8 b1 = *(const short8*)&ktc[(32 + l31) * 64 + ch];
            s0 = mfma32(aq[ks], b0, s0);
            s1 = mfma32(aq[ks], b1, s1);
        }
        __builtin_amdgcn_s_setprio(0);

        // --- normalized attn stores (fp32, nontemporal) + bf16 P into pq[cur] ---
        float* aB = attnB + (size_t)(wave * 32 + 4 * h5) * N_ + kti * 64 + l31;
        unsigned short* pqw = pq + cur * 9216 + (wave * 32 + 4 * h5) * 72 + l31;
#pragma unroll
        for (int r = 0; r < 16; ++r) {
            int ro = (r & 3) + 8 * (r >> 2);
            float p0 = __expf(s0[r] * SCALE_) * rv[r];
            float p1 = __expf(s1[r] * SCALE_) * rv[r];
            __builtin_nontemporal_store(p0, aB + (size_t)ro * N_);
            __builtin_nontemporal_store(p1, aB + (size_t)ro * N_ + 32);
            pqw[ro * 72] = f2bf(p0);
            pqw[ro * 72 + 32] = f2bf(p1);
        }

        // --- single barrier: staging/V retired (vmcnt<=32), stores may linger ---
        asm volatile("s_waitcnt vmcnt(32) lgkmcnt(0)\n\ts_barrier" ::: "memory");
        __builtin_amdgcn_sched_barrier(0);

        // --- PV from pq[cur], vt[cur] ---
        __builtin_amdgcn_s_setprio(1);
#pragma unroll
        for (int ks = 0; ks < 4; ++ks) {
            short8 ap = *(const short8*)&pq[cur * 9216 + (wave * 32 + l31) * 72 + ks * 16 + h5 * 8];
            int wv0 = (ks * 8 + h5 * 4) ^ (((l31 >> 3) & 7) << 2);
            short8 bv0 = *(const short8*)&vt[cur * 4608 + l31 * 72 + 2 * wv0];
            int dch = 32 + l31;
            int wv1 = (ks * 8 + h5 * 4) ^ (((dch >> 3) & 7) << 2);
            short8 bv1 = *(const short8*)&vt[cur * 4608 + dch * 72 + 2 * wv1];
            oa0 = mfma32(ap, bv0, oa0);
            oa1 = mfma32(ap, bv1, oa1);
        }
        __builtin_amdgcn_s_setprio(0);

        // --- V^T for next tile into vt[cur^1] ---
        if (kti < 31) WRITEV(cur ^ 1);
    }

    // ---- write O (bf16, [B,N,C]) ----
#pragma unroll
    for (int r = 0; r < 16; ++r) {
        int qrw = q0 + wave * 32 + 4 * h5 + (r & 3) + 8 * (r >> 2);
        size_t ob = (size_t)(b * N_ + qrw) * C_ + h * 64 + l31;
        o_out[ob] = f2bf(oa0[r]);
        o_out[ob + 32] = f2bf(oa1[r]);
    }
#undef WRITEV
}

extern "C" void kernel_launch(void* const* d_in, const int* in_sizes, int n_in,
                              void* d_out, int out_size, void* d_ws, size_t ws_size,
                              hipStream_t stream) {
    (void)in_sizes; (void)n_in; (void)out_size; (void)ws_size;
    const float* x      = (const float*)d_in[0];
    const float* w_qkv  = (const float*)d_in[1];
    const float* w_proj = (const float*)d_in[2];
    const float* b_proj = (const float*)d_in[3];

    float* out  = (float*)d_out;                       // [2,2048,1024] fp32
    float* attn = out + (size_t)B_ * N_ * C_;          // [2,16,2048,2048] fp32

    unsigned short* x_b     = (unsigned short*)d_ws;            // 4096x1024 (dead after qkv GEMM)
    unsigned short* wqkv_b  = x_b + (size_t)4096 * 1024;        // 3072x1024
    unsigned short* wproj_b = wqkv_b + (size_t)3072 * 1024;     // 1024x1024
    unsigned short* qkv_b   = wproj_b + (size_t)1024 * 1024;    // 4096x3072
    unsigned short* o_b     = qkv_b + (size_t)4096 * 3072;      // 4096x1024
    float* rinv = (float*)x_b;                                  // reuse dead region

    cvt_all<<<8192, 256, 0, stream>>>(x, w_qkv, w_proj, x_b, wqkv_b, wproj_b);

    // qkv: 32 by x 24 bx tiles; per-XCD region 8x12 (regions in 4x2 grid)
    gemm_bt<1, 128><<<768, 256, 0, stream>>>(
        x_b, wqkv_b, qkv_b, nullptr, nullptr, 4096, 3072, 1024, 2, 12);

    attn_sums<<<1024, 128, 0, stream>>>(qkv_b, rinv);
    attn_write<<<512, 256, 0, stream>>>(qkv_b, rinv, attn, o_b);

    // proj: 64 by x 8 bx tiles; per-XCD region 8x8 (regions in 8x1 grid)
    gemm_bt<0, 64><<<512, 256, 0, stream>>>(
        o_b, wproj_b, nullptr, out, b_proj, 4096, 1024, 1024, 1, 8);
}